// Round 1
// baseline (94.193 us; speedup 1.0000x reference)
//
#include <hip/hip_runtime.h>
#include <math.h>

using f32x4 = __attribute__((ext_vector_type(4))) float;
using s16x8 = __attribute__((ext_vector_type(8))) short;
using u16x8 = __attribute__((ext_vector_type(8))) unsigned short;
using u16x4 = __attribute__((ext_vector_type(4))) unsigned short;

static constexpr int KD = 1024;
static constexpr int ND = 1024;
static constexpr int BM = 128, BN = 128, BK = 32;
static constexpr int LDP = 56;   // LDS row pitch (112 B): spreads b128 frag reads over all 8 16B slots

__device__ inline unsigned short rne_bf16(float f) {
  unsigned u = __builtin_bit_cast(unsigned, f);
  u += 0x7FFFu + ((u >> 16) & 1u);
  return (unsigned short)(u >> 16);
}

// weights: cos/sin + transpose to [N][K] bf16 via LDS 32x32 tile
__global__ void qil_prep(const float* __restrict__ theta, const float* __restrict__ phi,
                         const float* __restrict__ tn, const float* __restrict__ pn,
                         unsigned short* __restrict__ WcT, unsigned short* __restrict__ WsT) {
  __shared__ float tc[32][33];
  __shared__ float ts[32][33];
  const int tx = threadIdx.x, ty = threadIdx.y;           // 32 x 8
  const int k0 = blockIdx.y * 32, o0 = blockIdx.x * 32;
  #pragma unroll
  for (int r = 0; r < 4; ++r) {
    int lk = ty + r * 8;
    int idx = (k0 + lk) * ND + o0 + tx;
    tc[lk][tx] = cosf(theta[idx] + tn[idx]);
    ts[lk][tx] = sinf(phi[idx] + pn[idx]);
  }
  __syncthreads();
  #pragma unroll
  for (int r = 0; r < 4; ++r) {
    int lo = ty + r * 8;
    int o = o0 + lo, k = k0 + tx;
    WcT[(size_t)o * KD + k] = rne_bf16(tc[tx][lo]);
    WsT[(size_t)o * KD + k] = rne_bf16(ts[tx][lo]);
  }
}

__global__ __launch_bounds__(256, 2)
void qil_gemm(const float* __restrict__ x, const unsigned short* __restrict__ WcT,
              const unsigned short* __restrict__ WsT, float* __restrict__ out) {
  __shared__ unsigned short lds[3 * BM * LDP];            // 42 KB
  unsigned short* Al  = lds;
  unsigned short* Bcl = lds + BM * LDP;
  unsigned short* Bsl = lds + 2 * BM * LDP;

  const int tid  = threadIdx.x;
  const int lane = tid & 63;
  const int wave = tid >> 6;
  const int wm = wave >> 1, wn = wave & 1;
  const int bm = blockIdx.x * BM;
  const int bn = blockIdx.y * BN;

  f32x4 accR[4][4] = {};
  f32x4 accI[4][4] = {};

  float4 aReg[4];
  u16x8 bcReg[2], bsReg[2];

  auto issue = [&](int kt) {
    const int kb = kt * BK;
    #pragma unroll
    for (int j = 0; j < 4; ++j) {                          // A: 128x32 fp32, 4 float4/thread
      int c = j * 256 + tid;
      int row = c >> 3, col = (c & 7) * 4;
      aReg[j] = *reinterpret_cast<const float4*>(x + (size_t)(bm + row) * KD + kb + col);
    }
    #pragma unroll
    for (int j = 0; j < 2; ++j) {                          // B: 128x32 bf16 each, 2 u16x8/thread
      int c = j * 256 + tid;
      int row = c >> 2, col = (c & 3) * 8;
      bcReg[j] = *reinterpret_cast<const u16x8*>(WcT + (size_t)(bn + row) * KD + kb + col);
      bsReg[j] = *reinterpret_cast<const u16x8*>(WsT + (size_t)(bn + row) * KD + kb + col);
    }
  };

  issue(0);

  const int fr = lane & 15;
  const int kq = (lane >> 4) * 8;

  for (int kt = 0; kt < KD / BK; ++kt) {
    __syncthreads();                                       // all waves done reading prev tile
    #pragma unroll
    for (int j = 0; j < 4; ++j) {                          // A write (convert fp32 -> bf16)
      int c = j * 256 + tid;
      int row = c >> 3, col = (c & 7) * 4;
      u16x4 v;
      v[0] = rne_bf16(aReg[j].x); v[1] = rne_bf16(aReg[j].y);
      v[2] = rne_bf16(aReg[j].z); v[3] = rne_bf16(aReg[j].w);
      *reinterpret_cast<u16x4*>(Al + row * LDP + col) = v;
    }
    #pragma unroll
    for (int j = 0; j < 2; ++j) {                          // B writes
      int c = j * 256 + tid;
      int row = c >> 2, col = (c & 3) * 8;
      *reinterpret_cast<u16x8*>(Bcl + row * LDP + col) = bcReg[j];
      *reinterpret_cast<u16x8*>(Bsl + row * LDP + col) = bsReg[j];
    }
    __syncthreads();                                       // tile ready
    if (kt + 1 < KD / BK) issue(kt + 1);                   // prefetch hides under compute

    s16x8 av[4];
    #pragma unroll
    for (int f = 0; f < 4; ++f)
      av[f] = *reinterpret_cast<const s16x8*>(Al + (wm * 64 + f * 16 + fr) * LDP + kq);
    #pragma unroll
    for (int g = 0; g < 4; ++g) {
      s16x8 bc = *reinterpret_cast<const s16x8*>(Bcl + (wn * 64 + g * 16 + fr) * LDP + kq);
      s16x8 bs = *reinterpret_cast<const s16x8*>(Bsl + (wn * 64 + g * 16 + fr) * LDP + kq);
      #pragma unroll
      for (int f = 0; f < 4; ++f) {
        accR[f][g] = __builtin_amdgcn_mfma_f32_16x16x32_bf16(av[f], bc, accR[f][g], 0, 0, 0);
        accI[f][g] = __builtin_amdgcn_mfma_f32_16x16x32_bf16(av[f], bs, accI[f][g], 0, 0, 0);
      }
    }
  }

  // epilogue: out = sqrt(re^2 + im^2), C/D layout col=lane&15, row=(lane>>4)*4+reg
  #pragma unroll
  for (int f = 0; f < 4; ++f) {
    #pragma unroll
    for (int g = 0; g < 4; ++g) {
      #pragma unroll
      for (int r = 0; r < 4; ++r) {
        int row = wm * 64 + f * 16 + (lane >> 4) * 4 + r;
        int col = wn * 64 + g * 16 + fr;
        float re = accR[f][g][r];
        float im = accI[f][g][r];
        out[(size_t)(bm + row) * ND + bn + col] = sqrtf(re * re + im * im);
      }
    }
  }
}

extern "C" void kernel_launch(void* const* d_in, const int* in_sizes, int n_in,
                              void* d_out, int out_size, void* d_ws, size_t ws_size,
                              hipStream_t stream) {
  const float* x     = (const float*)d_in[0];
  const float* theta = (const float*)d_in[1];
  const float* phi   = (const float*)d_in[2];
  const float* tn    = (const float*)d_in[3];
  const float* pn    = (const float*)d_in[4];
  float* out = (float*)d_out;

  unsigned short* WcT = (unsigned short*)d_ws;             // 2 MB
  unsigned short* WsT = WcT + (size_t)ND * KD;             // 2 MB

  qil_prep<<<dim3(32, 32), dim3(32, 8), 0, stream>>>(theta, phi, tn, pn, WcT, WsT);

  const int MB = in_sizes[0] / KD;                         // 16384 rows
  qil_gemm<<<dim3(MB / BM, ND / BN), dim3(256), 0, stream>>>(x, WcT, WsT, out);
}

// Round 2
// 91.150 us; speedup vs baseline: 1.0334x; 1.0334x over previous
//
#include <hip/hip_runtime.h>
#include <math.h>

using f32x4 = __attribute__((ext_vector_type(4))) float;
using s16x8 = __attribute__((ext_vector_type(8))) short;
using u16x8 = __attribute__((ext_vector_type(8))) unsigned short;

static constexpr int KD = 1024;
static constexpr int ND = 1024;
static constexpr int BM = 256, BN = 128, BK = 64;
static constexpr int NT = KD / BK;   // 16 K-tiles

__device__ inline unsigned short rne_bf16(float f) {
  unsigned u = __builtin_bit_cast(unsigned, f);
  u += 0x7FFFu + ((u >> 16) & 1u);
  return (unsigned short)(u >> 16);
}

// Weights: cos/sin -> bf16, transpose to [N][K], K pre-swizzled within each
// 64-block so a LINEAR global_load_lds produces the XOR-swizzled LDS layout.
__global__ void qil_prep(const float* __restrict__ theta, const float* __restrict__ phi,
                         const float* __restrict__ tn, const float* __restrict__ pn,
                         unsigned short* __restrict__ WcT, unsigned short* __restrict__ WsT) {
  __shared__ float tc[32][33];
  __shared__ float ts[32][33];
  const int tx = threadIdx.x, ty = threadIdx.y;           // 32 x 8
  const int k0 = blockIdx.y * 32, o0 = blockIdx.x * 32;
  #pragma unroll
  for (int r = 0; r < 4; ++r) {
    int lk = ty + r * 8;
    int idx = (k0 + lk) * ND + o0 + tx;
    tc[lk][tx] = cosf(theta[idx] + tn[idx]);
    ts[lk][tx] = sinf(phi[idx] + pn[idx]);
  }
  __syncthreads();
  #pragma unroll
  for (int r = 0; r < 4; ++r) {
    int lo = ty + r * 8;
    int o = o0 + lo, k = k0 + tx;
    int ksw = (k & ~63) | ((k & 63) ^ ((o & 7) << 3));    // T2 pre-swizzle
    WcT[(size_t)o * KD + ksw] = rne_bf16(tc[tx][lo]);
    WsT[(size_t)o * KD + ksw] = rne_bf16(ts[tx][lo]);
  }
}

__global__ __launch_bounds__(512, 2)
void qil_gemm(const float* __restrict__ x, const unsigned short* __restrict__ WcT,
              const unsigned short* __restrict__ WsT, float* __restrict__ out) {
  // 128 KB LDS: A 2x(256x64), Bc 2x(128x64), Bs 2x(128x64) bf16
  __shared__ unsigned short lds[65536];
  unsigned short* ldsA = lds;              // 2 x 16384
  unsigned short* ldsC = lds + 32768;      // 2 x 8192
  unsigned short* ldsS = lds + 49152;      // 2 x 8192

  const int tid  = threadIdx.x;
  const int lane = tid & 63;
  const int wave = tid >> 6;
  const int wm = wave >> 2;                // 0..1  (M half, 128 rows)
  const int wn = wave & 3;                 // 0..3  (32-col quarter)

  // XCD swizzle: cluster same-M blocks on one XCD (x reuse in L2)
  const int bid = blockIdx.x;
  const int xcd = bid & 7, w8 = bid >> 3;
  const int mt = ((w8 & 7) << 3) | xcd;    // 0..63
  const int nt = w8 >> 3;                  // 0..7
  const int bm = mt * BM;
  const int bn = nt * BN;

  const int fr = lane & 15;
  const int kg = lane >> 4;                // 0..3
  const int kq = kg * 8;

  f32x4 accR[8][2] = {};
  f32x4 accI[8][2] = {};
  float4 aReg[4][2];

  auto issueA = [&](int t) {               // 8 global_load_dwordx4 -> regs
    const int kb = t * BK;
    #pragma unroll
    for (int j = 0; j < 4; ++j) {
      int c = tid + j * 512;
      int row = c >> 3, col8 = (c & 7) * 8;
      const float* p = x + (size_t)(bm + row) * KD + kb + col8;
      aReg[j][0] = *reinterpret_cast<const float4*>(p);
      aReg[j][1] = *reinterpret_cast<const float4*>(p + 4);
    }
  };

  auto issueB = [&](int t, int d) {        // 4 global_load_lds per wave
    const int kb = t * BK;
    unsigned short* Cb = ldsC + d * 8192;
    unsigned short* Sb = ldsS + d * 8192;
    #pragma unroll
    for (int q = 0; q < 2; ++q) {
      int rb = (wave * 2 + q) * 8;         // 8 rows per call
      const unsigned short* gc = WcT + (size_t)(bn + rb + (lane >> 3)) * KD + kb + (lane & 7) * 8;
      const unsigned short* gs = WsT + (size_t)(bn + rb + (lane >> 3)) * KD + kb + (lane & 7) * 8;
      __builtin_amdgcn_global_load_lds(
          (const __attribute__((address_space(1))) unsigned int*)gc,
          (__attribute__((address_space(3))) unsigned int*)(Cb + rb * 64), 16, 0, 0);
      __builtin_amdgcn_global_load_lds(
          (const __attribute__((address_space(1))) unsigned int*)gs,
          (__attribute__((address_space(3))) unsigned int*)(Sb + rb * 64), 16, 0, 0);
    }
  };

  auto cvtWriteA = [&](int d) {            // bf16 convert + swizzled ds_write_b128
    unsigned short* Ab = ldsA + d * 16384;
    #pragma unroll
    for (int j = 0; j < 4; ++j) {
      int c = tid + j * 512;
      int row = c >> 3, col8 = (c & 7) * 8;
      u16x8 v;
      v[0] = rne_bf16(aReg[j][0].x); v[1] = rne_bf16(aReg[j][0].y);
      v[2] = rne_bf16(aReg[j][0].z); v[3] = rne_bf16(aReg[j][0].w);
      v[4] = rne_bf16(aReg[j][1].x); v[5] = rne_bf16(aReg[j][1].y);
      v[6] = rne_bf16(aReg[j][1].z); v[7] = rne_bf16(aReg[j][1].w);
      int off = row * 64 + (col8 ^ ((row & 7) << 3));
      *reinterpret_cast<u16x8*>(Ab + off) = v;
    }
  };

  // prologue: stage tile 0
  issueA(0);
  issueB(0, 0);
  cvtWriteA(0);
  __syncthreads();

  for (int t = 0; t < NT; ++t) {
    const int d = t & 1;
    unsigned short* Ab = ldsA + d * 16384;
    unsigned short* Cb = ldsC + d * 8192;
    unsigned short* Sb = ldsS + d * 8192;
    const bool pf = (t + 1 < NT);

    if (pf) issueA(t + 1);

    s16x8 av[8];
    s16x8 bc[2], bs[2];

    // ---- kstep 0 ----
    #pragma unroll
    for (int f = 0; f < 8; ++f) {
      int r = wm * 128 + f * 16 + fr;
      av[f] = *reinterpret_cast<const s16x8*>(Ab + r * 64 + (kq ^ ((r & 7) << 3)));
    }
    #pragma unroll
    for (int g = 0; g < 2; ++g) {
      int n = wn * 32 + g * 16 + fr;
      bc[g] = *reinterpret_cast<const s16x8*>(Cb + n * 64 + (kq ^ ((n & 7) << 3)));
      bs[g] = *reinterpret_cast<const s16x8*>(Sb + n * 64 + (kq ^ ((n & 7) << 3)));
    }
    if (pf) issueB(t + 1, d ^ 1);
    __builtin_amdgcn_s_setprio(1);
    #pragma unroll
    for (int g = 0; g < 2; ++g)
      #pragma unroll
      for (int f = 0; f < 8; ++f) {
        accR[f][g] = __builtin_amdgcn_mfma_f32_16x16x32_bf16(av[f], bc[g], accR[f][g], 0, 0, 0);
        accI[f][g] = __builtin_amdgcn_mfma_f32_16x16x32_bf16(av[f], bs[g], accI[f][g], 0, 0, 0);
      }
    __builtin_amdgcn_s_setprio(0);

    // ---- kstep 1 ----
    #pragma unroll
    for (int f = 0; f < 8; ++f) {
      int r = wm * 128 + f * 16 + fr;
      av[f] = *reinterpret_cast<const s16x8*>(Ab + r * 64 + ((32 + kq) ^ ((r & 7) << 3)));
    }
    #pragma unroll
    for (int g = 0; g < 2; ++g) {
      int n = wn * 32 + g * 16 + fr;
      bc[g] = *reinterpret_cast<const s16x8*>(Cb + n * 64 + ((32 + kq) ^ ((n & 7) << 3)));
      bs[g] = *reinterpret_cast<const s16x8*>(Sb + n * 64 + ((32 + kq) ^ ((n & 7) << 3)));
    }
    if (pf) cvtWriteA(d ^ 1);
    __builtin_amdgcn_s_setprio(1);
    #pragma unroll
    for (int g = 0; g < 2; ++g)
      #pragma unroll
      for (int f = 0; f < 8; ++f) {
        accR[f][g] = __builtin_amdgcn_mfma_f32_16x16x32_bf16(av[f], bc[g], accR[f][g], 0, 0, 0);
        accI[f][g] = __builtin_amdgcn_mfma_f32_16x16x32_bf16(av[f], bs[g], accI[f][g], 0, 0, 0);
      }
    __builtin_amdgcn_s_setprio(0);

    __syncthreads();                       // one barrier per K-tile
  }

  // epilogue: out = sqrt(re^2+im^2); C/D: col=lane&15, row=(lane>>4)*4+reg
  #pragma unroll
  for (int f = 0; f < 8; ++f) {
    #pragma unroll
    for (int g = 0; g < 2; ++g) {
      int row = bm + wm * 128 + f * 16 + kg * 4;
      int col = bn + wn * 32 + g * 16 + fr;
      #pragma unroll
      for (int r = 0; r < 4; ++r) {
        float re = accR[f][g][r];
        float im = accI[f][g][r];
        out[(size_t)(row + r) * ND + col] = sqrtf(re * re + im * im);
      }
    }
  }
}

extern "C" void kernel_launch(void* const* d_in, const int* in_sizes, int n_in,
                              void* d_out, int out_size, void* d_ws, size_t ws_size,
                              hipStream_t stream) {
  const float* x     = (const float*)d_in[0];
  const float* theta = (const float*)d_in[1];
  const float* phi   = (const float*)d_in[2];
  const float* tn    = (const float*)d_in[3];
  const float* pn    = (const float*)d_in[4];
  float* out = (float*)d_out;

  unsigned short* WcT = (unsigned short*)d_ws;             // 2 MB
  unsigned short* WsT = WcT + (size_t)ND * KD;             // 2 MB

  qil_prep<<<dim3(32, 32), dim3(32, 8), 0, stream>>>(theta, phi, tn, pn, WcT, WsT);

  const int MB = in_sizes[0] / KD;                         // 16384 rows
  const int nblk = (MB / BM) * (ND / BN);                  // 64*8 = 512
  qil_gemm<<<dim3(nblk), dim3(512), 0, stream>>>(x, WcT, WsT, out);
}

// Round 3
// 89.075 us; speedup vs baseline: 1.0574x; 1.0233x over previous
//
#include <hip/hip_runtime.h>
#include <math.h>

using f32x4 = __attribute__((ext_vector_type(4))) float;
using s16x8 = __attribute__((ext_vector_type(8))) short;
using u16x8 = __attribute__((ext_vector_type(8))) unsigned short;
using u16x4 = __attribute__((ext_vector_type(4))) unsigned short;

static constexpr int KD = 1024, ND = 1024;
static constexpr int BM = 256, BN = 128, BK = 64;
static constexpr int NT = KD / BK;          // 16 K-tiles
static constexpr int ATB = BM * BK * 2;     // 32768 B per A tile
static constexpr int BTB = BN * BK * 2;     // 16384 B per B tile

#define BARRIER() asm volatile("s_barrier" ::: "memory")
#define WAITV(n)  asm volatile("s_waitcnt vmcnt(" #n ")" ::: "memory")

__device__ inline unsigned short rne_bf16(float f) {
  unsigned u = __builtin_bit_cast(unsigned, f);
  u += 0x7FFFu + ((u >> 16) & 1u);
  return (unsigned short)(u >> 16);
}

__device__ inline void gl16(const void* g, void* l) {
  __builtin_amdgcn_global_load_lds((const __attribute__((address_space(1))) unsigned int*)g,
                                   (__attribute__((address_space(3))) unsigned int*)l, 16, 0, 0);
}

#define MFMA(a, b, c) __builtin_amdgcn_mfma_f32_16x16x32_bf16(a, b, c, 0, 0, 0)

// ---------------- new path: blocked + swizzled operand prep ----------------

// x fp32 -> bf16, tile-blocked [mt][kt][32768B], bytes pre-swizzled:
// element [r][k] of tile at byte (r*128 + k*2) ^ ((r&7)<<4)
__global__ void qil_prep_x(const float* __restrict__ x, unsigned short* __restrict__ xb) {
  int u = blockIdx.x * 256 + threadIdx.x;        // 2^21 threads
  int m = u >> 7, k8 = u & 127;
  int kt = k8 >> 3, k16 = k8 & 7;
  int mt = m >> 8, r = m & 255;
  const float* p = x + (size_t)m * KD + kt * 64 + k16 * 8;
  float4 a = *reinterpret_cast<const float4*>(p);
  float4 b = *reinterpret_cast<const float4*>(p + 4);
  u16x8 v;
  v[0] = rne_bf16(a.x); v[1] = rne_bf16(a.y); v[2] = rne_bf16(a.z); v[3] = rne_bf16(a.w);
  v[4] = rne_bf16(b.x); v[5] = rne_bf16(b.y); v[6] = rne_bf16(b.z); v[7] = rne_bf16(b.w);
  int o = (r * 128 + k16 * 16) ^ ((r & 7) << 4);
  *reinterpret_cast<u16x8*>((char*)xb + (size_t)(mt * 16 + kt) * ATB + o) = v;
}

// weights: cos/sin -> bf16, transpose to [n][k], tile-blocked [nt][kt][16384B], swizzled
__global__ void qil_prep_w2(const float* __restrict__ theta, const float* __restrict__ phi,
                            const float* __restrict__ tn, const float* __restrict__ pn,
                            unsigned short* __restrict__ WcB, unsigned short* __restrict__ WsB) {
  __shared__ float tc[32][33];
  __shared__ float ts[32][33];
  const int tx = threadIdx.x, ty = threadIdx.y;   // 32 x 8
  const int k0 = blockIdx.y * 32, o0 = blockIdx.x * 32;
  #pragma unroll
  for (int r = 0; r < 4; ++r) {
    int lk = ty + r * 8;
    int idx = (k0 + lk) * ND + o0 + tx;
    tc[lk][tx] = cosf(theta[idx] + tn[idx]);
    ts[lk][tx] = sinf(phi[idx] + pn[idx]);
  }
  __syncthreads();
  int s = ty * 32 + tx;
  int nl = s >> 3, q = s & 7;
  int n = o0 + nl;
  int kt = k0 >> 6;
  int kk0 = (k0 & 63) + q * 4;
  int off = ((n & 127) * 128 + kk0 * 2) ^ ((n & 7) << 4);
  size_t base = (size_t)((n >> 7) * 16 + kt) * BTB + off;
  u16x4 vc, vs;
  #pragma unroll
  for (int j = 0; j < 4; ++j) {
    vc[j] = rne_bf16(tc[q * 4 + j][nl]);
    vs[j] = rne_bf16(ts[q * 4 + j][nl]);
  }
  *reinterpret_cast<u16x4*>((char*)WcB + base) = vc;
  *reinterpret_cast<u16x4*>((char*)WsB + base) = vs;
}

// 8-phase dual-GEMM: out = sqrt((x@cos)^2 + (x@sin)^2)
__global__ __launch_bounds__(512, 2)
void qil_gemm8(const unsigned short* __restrict__ xb, const unsigned short* __restrict__ WcB,
               const unsigned short* __restrict__ WsB, float* __restrict__ out) {
  __shared__ char ldsb[131072];                  // 2 x {A 32K, Bc 16K, Bs 16K}
  const int tid = threadIdx.x, lane = tid & 63, wave = tid >> 6;
  const int wm = wave >> 2, wn = wave & 3;
  const int bid = blockIdx.x;
  const int xcd = bid & 7, w8 = bid >> 3;
  const int mt = ((w8 & 7) << 3) | xcd;          // 0..63
  const int nt = w8 >> 3;                        // 0..7

  const int fr = lane & 15, kg = lane >> 4;
  const int sw = (fr & 7) << 4;
  const int ak0 = (kg * 16) ^ sw;                // kstep 0 byte offset in row
  const int ak1 = (64 + kg * 16) ^ sw;           // kstep 1
  const int abase = (wm * 128 + fr) * 128;
  const int bbase = (wn * 32 + fr) * 128;

  const size_t xblk = (size_t)(mt * 16) * ATB;
  const size_t cblk = (size_t)(nt * 16) * BTB;
  const int stg = wave * 1024 + lane * 16;

  f32x4 accR[8][2] = {}, accI[8][2] = {};
  s16x8 av[4][2], bcx[2][2], bsx[2][2];

  auto stA = [&](int t, int h) {                 // one A half-tile: 2 gload_lds
    char* d = ldsb + (t & 1) * 65536 + h * 16384 + stg;
    const char* s = (const char*)xb + xblk + (size_t)t * ATB + h * 16384 + stg;
    gl16(s, d); gl16(s + 8192, d + 8192);
  };
  auto stC = [&](int t) {                        // Bc tile: 2 gload_lds
    char* d = ldsb + (t & 1) * 65536 + 32768 + stg;
    const char* s = (const char*)WcB + cblk + (size_t)t * BTB + stg;
    gl16(s, d); gl16(s + 8192, d + 8192);
  };
  auto stS = [&](int t) {                        // Bs tile: 2 gload_lds
    char* d = ldsb + (t & 1) * 65536 + 49152 + stg;
    const char* s = (const char*)WsB + cblk + (size_t)t * BTB + stg;
    gl16(s, d); gl16(s + 8192, d + 8192);
  };

  // prologue: stage tile 0 (issue order A0,A1,Bc,Bs), wait all but Bs
  stA(0, 0); stA(0, 1); stC(0); stS(0);
  WAITV(2); BARRIER();

  for (int t = 0; t < NT; ++t) {
    char* Ab = ldsb + (t & 1) * 65536;
    char* Cb = Ab + 32768;
    char* Sb = Ab + 49152;
    const bool pf = (t + 1 < NT);

    // ---- phase q0: A f-half0 + Bc reads; MFMA R (f0..3) ----
    #pragma unroll
    for (int f = 0; f < 4; ++f) {
      av[f][0] = *(const s16x8*)(Ab + abase + f * 2048 + ak0);
      av[f][1] = *(const s16x8*)(Ab + abase + f * 2048 + ak1);
    }
    #pragma unroll
    for (int g = 0; g < 2; ++g) {
      bcx[g][0] = *(const s16x8*)(Cb + bbase + g * 2048 + ak0);
      bcx[g][1] = *(const s16x8*)(Cb + bbase + g * 2048 + ak1);
    }
    if (pf) stA(t + 1, 0);
    BARRIER();
    __builtin_amdgcn_s_setprio(1);
    #pragma unroll
    for (int g = 0; g < 2; ++g)
      #pragma unroll
      for (int f = 0; f < 4; ++f) {
        accR[f][g] = MFMA(av[f][0], bcx[g][0], accR[f][g]);
        accR[f][g] = MFMA(av[f][1], bcx[g][1], accR[f][g]);
      }
    __builtin_amdgcn_s_setprio(0);
    if (pf) { WAITV(2); } else { WAITV(0); }     // retire Bs(t) (tail: drain)
    BARRIER();

    // ---- phase q1: Bs reads; MFMA I (f0..3) ----
    #pragma unroll
    for (int g = 0; g < 2; ++g) {
      bsx[g][0] = *(const s16x8*)(Sb + bbase + g * 2048 + ak0);
      bsx[g][1] = *(const s16x8*)(Sb + bbase + g * 2048 + ak1);
    }
    if (pf) stA(t + 1, 1);
    BARRIER();
    __builtin_amdgcn_s_setprio(1);
    #pragma unroll
    for (int g = 0; g < 2; ++g)
      #pragma unroll
      for (int f = 0; f < 4; ++f) {
        accI[f][g] = MFMA(av[f][0], bsx[g][0], accI[f][g]);
        accI[f][g] = MFMA(av[f][1], bsx[g][1], accI[f][g]);
      }
    __builtin_amdgcn_s_setprio(0);
    BARRIER();

    // ---- phase q2: A f-half1 reads; MFMA R (f4..7) ----
    #pragma unroll
    for (int f = 0; f < 4; ++f) {
      av[f][0] = *(const s16x8*)(Ab + abase + 8192 + f * 2048 + ak0);
      av[f][1] = *(const s16x8*)(Ab + abase + 8192 + f * 2048 + ak1);
    }
    if (pf) stC(t + 1);
    BARRIER();
    __builtin_amdgcn_s_setprio(1);
    #pragma unroll
    for (int g = 0; g < 2; ++g)
      #pragma unroll
      for (int f = 0; f < 4; ++f) {
        accR[4 + f][g] = MFMA(av[f][0], bcx[g][0], accR[4 + f][g]);
        accR[4 + f][g] = MFMA(av[f][1], bcx[g][1], accR[4 + f][g]);
      }
    __builtin_amdgcn_s_setprio(0);
    BARRIER();

    // ---- phase q3: no reads; MFMA I (f4..7) ----
    if (pf) stS(t + 1);
    BARRIER();
    __builtin_amdgcn_s_setprio(1);
    #pragma unroll
    for (int g = 0; g < 2; ++g)
      #pragma unroll
      for (int f = 0; f < 4; ++f) {
        accI[4 + f][g] = MFMA(av[f][0], bsx[g][0], accI[4 + f][g]);
        accI[4 + f][g] = MFMA(av[f][1], bsx[g][1], accI[4 + f][g]);
      }
    __builtin_amdgcn_s_setprio(0);
    if (pf) { WAITV(2); }                        // retire A0,A1,Bc of t+1
    BARRIER();
  }

  // epilogue: C/D layout col=lane&15, row=(lane>>4)*4+reg
  const int bm = mt * BM, bn = nt * BN;
  #pragma unroll
  for (int f = 0; f < 8; ++f) {
    #pragma unroll
    for (int g = 0; g < 2; ++g) {
      int row = bm + wm * 128 + f * 16 + kg * 4;
      int col = bn + wn * 32 + g * 16 + fr;
      #pragma unroll
      for (int r = 0; r < 4; ++r) {
        float re = accR[f][g][r];
        float im = accI[f][g][r];
        out[(size_t)(row + r) * ND + col] = sqrtf(re * re + im * im);
      }
    }
  }
}

// ---------------- fallback path (round-2 kernels, needs only 4 MB ws) ----------------

static constexpr int FLDP_NA = 0; // silence unused warnings placeholder

__global__ void qil_prep_fb(const float* __restrict__ theta, const float* __restrict__ phi,
                            const float* __restrict__ tn, const float* __restrict__ pn,
                            unsigned short* __restrict__ WcT, unsigned short* __restrict__ WsT) {
  __shared__ float tc[32][33];
  __shared__ float ts[32][33];
  const int tx = threadIdx.x, ty = threadIdx.y;
  const int k0 = blockIdx.y * 32, o0 = blockIdx.x * 32;
  #pragma unroll
  for (int r = 0; r < 4; ++r) {
    int lk = ty + r * 8;
    int idx = (k0 + lk) * ND + o0 + tx;
    tc[lk][tx] = cosf(theta[idx] + tn[idx]);
    ts[lk][tx] = sinf(phi[idx] + pn[idx]);
  }
  __syncthreads();
  #pragma unroll
  for (int r = 0; r < 4; ++r) {
    int lo = ty + r * 8;
    int o = o0 + lo, k = k0 + tx;
    int ksw = (k & ~63) | ((k & 63) ^ ((o & 7) << 3));
    WcT[(size_t)o * KD + ksw] = rne_bf16(tc[tx][lo]);
    WsT[(size_t)o * KD + ksw] = rne_bf16(ts[tx][lo]);
  }
}

__global__ __launch_bounds__(512, 2)
void qil_gemm_fb(const float* __restrict__ x, const unsigned short* __restrict__ WcT,
                 const unsigned short* __restrict__ WsT, float* __restrict__ out) {
  __shared__ unsigned short lds[65536];
  unsigned short* ldsA = lds;
  unsigned short* ldsC = lds + 32768;
  unsigned short* ldsS = lds + 49152;

  const int tid  = threadIdx.x;
  const int lane = tid & 63;
  const int wave = tid >> 6;
  const int wm = wave >> 2, wn = wave & 3;
  const int bid = blockIdx.x;
  const int xcd = bid & 7, w8 = bid >> 3;
  const int mt = ((w8 & 7) << 3) | xcd;
  const int nt = w8 >> 3;
  const int bm = mt * BM, bn = nt * BN;
  const int fr = lane & 15, kg = lane >> 4, kq = kg * 8;

  f32x4 accR[8][2] = {};
  f32x4 accI[8][2] = {};
  float4 aReg[4][2];

  auto issueA = [&](int t) {
    const int kb = t * BK;
    #pragma unroll
    for (int j = 0; j < 4; ++j) {
      int c = tid + j * 512;
      int row = c >> 3, col8 = (c & 7) * 8;
      const float* p = x + (size_t)(bm + row) * KD + kb + col8;
      aReg[j][0] = *reinterpret_cast<const float4*>(p);
      aReg[j][1] = *reinterpret_cast<const float4*>(p + 4);
    }
  };
  auto issueB = [&](int t, int d) {
    const int kb = t * BK;
    unsigned short* Cb = ldsC + d * 8192;
    unsigned short* Sb = ldsS + d * 8192;
    #pragma unroll
    for (int q = 0; q < 2; ++q) {
      int rb = (wave * 2 + q) * 8;
      const unsigned short* gc = WcT + (size_t)(bn + rb + (lane >> 3)) * KD + kb + (lane & 7) * 8;
      const unsigned short* gs = WsT + (size_t)(bn + rb + (lane >> 3)) * KD + kb + (lane & 7) * 8;
      gl16(gc, Cb + rb * 64);
      gl16(gs, Sb + rb * 64);
    }
  };
  auto cvtWriteA = [&](int d) {
    unsigned short* Ab = ldsA + d * 16384;
    #pragma unroll
    for (int j = 0; j < 4; ++j) {
      int c = tid + j * 512;
      int row = c >> 3, col8 = (c & 7) * 8;
      u16x8 v;
      v[0] = rne_bf16(aReg[j][0].x); v[1] = rne_bf16(aReg[j][0].y);
      v[2] = rne_bf16(aReg[j][0].z); v[3] = rne_bf16(aReg[j][0].w);
      v[4] = rne_bf16(aReg[j][1].x); v[5] = rne_bf16(aReg[j][1].y);
      v[6] = rne_bf16(aReg[j][1].z); v[7] = rne_bf16(aReg[j][1].w);
      int off = row * 64 + (col8 ^ ((row & 7) << 3));
      *reinterpret_cast<u16x8*>(Ab + off) = v;
    }
  };

  issueA(0);
  issueB(0, 0);
  cvtWriteA(0);
  __syncthreads();

  for (int t = 0; t < NT; ++t) {
    const int d = t & 1;
    unsigned short* Ab = ldsA + d * 16384;
    unsigned short* Cb = ldsC + d * 8192;
    unsigned short* Sb = ldsS + d * 8192;
    const bool pf = (t + 1 < NT);

    if (pf) issueA(t + 1);

    s16x8 av[8];
    s16x8 bc[2], bs[2];

    #pragma unroll
    for (int f = 0; f < 8; ++f) {
      int r = wm * 128 + f * 16 + fr;
      av[f] = *reinterpret_cast<const s16x8*>(Ab + r * 64 + (kq ^ ((r & 7) << 3)));
    }
    #pragma unroll
    for (int g = 0; g < 2; ++g) {
      int n = wn * 32 + g * 16 + fr;
      bc[g] = *reinterpret_cast<const s16x8*>(Cb + n * 64 + (kq ^ ((n & 7) << 3)));
      bs[g] = *reinterpret_cast<const s16x8*>(Sb + n * 64 + (kq ^ ((n & 7) << 3)));
    }
    if (pf) issueB(t + 1, d ^ 1);
    __builtin_amdgcn_s_setprio(1);
    #pragma unroll
    for (int g = 0; g < 2; ++g)
      #pragma unroll
      for (int f = 0; f < 8; ++f) {
        accR[f][g] = MFMA(av[f], bc[g], accR[f][g]);
        accI[f][g] = MFMA(av[f], bs[g], accI[f][g]);
      }
    __builtin_amdgcn_s_setprio(0);

    #pragma unroll
    for (int f = 0; f < 8; ++f) {
      int r = wm * 128 + f * 16 + fr;
      av[f] = *reinterpret_cast<const s16x8*>(Ab + r * 64 + ((32 + kq) ^ ((r & 7) << 3)));
    }
    #pragma unroll
    for (int g = 0; g < 2; ++g) {
      int n = wn * 32 + g * 16 + fr;
      bc[g] = *reinterpret_cast<const s16x8*>(Cb + n * 64 + ((32 + kq) ^ ((n & 7) << 3)));
      bs[g] = *reinterpret_cast<const s16x8*>(Sb + n * 64 + ((32 + kq) ^ ((n & 7) << 3)));
    }
    if (pf) cvtWriteA(d ^ 1);
    __builtin_amdgcn_s_setprio(1);
    #pragma unroll
    for (int g = 0; g < 2; ++g)
      #pragma unroll
      for (int f = 0; f < 8; ++f) {
        accR[f][g] = MFMA(av[f], bc[g], accR[f][g]);
        accI[f][g] = MFMA(av[f], bs[g], accI[f][g]);
      }
    __builtin_amdgcn_s_setprio(0);

    __syncthreads();
  }

  #pragma unroll
  for (int f = 0; f < 8; ++f) {
    #pragma unroll
    for (int g = 0; g < 2; ++g) {
      int row = bm + wm * 128 + f * 16 + kg * 4;
      int col = bn + wn * 32 + g * 16 + fr;
      #pragma unroll
      for (int r = 0; r < 4; ++r) {
        float re = accR[f][g][r];
        float im = accI[f][g][r];
        out[(size_t)(row + r) * ND + col] = sqrtf(re * re + im * im);
      }
    }
  }
}

extern "C" void kernel_launch(void* const* d_in, const int* in_sizes, int n_in,
                              void* d_out, int out_size, void* d_ws, size_t ws_size,
                              hipStream_t stream) {
  const float* x     = (const float*)d_in[0];
  const float* theta = (const float*)d_in[1];
  const float* phi   = (const float*)d_in[2];
  const float* tn    = (const float*)d_in[3];
  const float* pn    = (const float*)d_in[4];
  float* out = (float*)d_out;

  const int MB = in_sizes[0] / KD;                         // 16384 rows
  const size_t wBytes = (size_t)ND * KD * 2;               // 2 MB per weight matrix
  const size_t xBytes = (size_t)MB * KD * 2;               // 32 MB
  const size_t need = 2 * wBytes + xBytes;

  if (ws_size >= need) {
    unsigned short* WcB = (unsigned short*)d_ws;
    unsigned short* WsB = WcB + (size_t)ND * KD;
    unsigned short* xb  = WsB + (size_t)ND * KD;
    qil_prep_w2<<<dim3(32, 32), dim3(32, 8), 0, stream>>>(theta, phi, tn, pn, WcB, WsB);
    qil_prep_x<<<dim3((MB * (KD / 8)) / 256), dim3(256), 0, stream>>>(x, xb);
    const int nblk = (MB / BM) * (ND / BN);                // 512
    qil_gemm8<<<dim3(nblk), dim3(512), 0, stream>>>(xb, WcB, WsB, out);
  } else {
    unsigned short* WcT = (unsigned short*)d_ws;
    unsigned short* WsT = WcT + (size_t)ND * KD;
    qil_prep_fb<<<dim3(32, 32), dim3(32, 8), 0, stream>>>(theta, phi, tn, pn, WcT, WsT);
    const int nblk = (MB / BM) * (ND / BN);
    qil_gemm_fb<<<dim3(nblk), dim3(512), 0, stream>>>(x, WcT, WsT, out);
  }
}